// Round 4
// baseline (273.004 us; speedup 1.0000x reference)
//
#include <hip/hip_runtime.h>
#include <math.h>

// Problem constants (match reference)
#define B_    8
#define L_    2048
#define D_    1024
#define NN    64        // NUM_NODES
#define NH    8         // NUM_HEADS
#define NSLOT 512       // NN*NH
#define NTOK  (B_*L_)   // 16384
#define CAP   1024      // per-(b,node) entry list capacity (mean occupancy 64)
#define MAXC  8         // max rescore candidates (margin window holds 2-4 typ.)

typedef __attribute__((ext_vector_type(8))) short short8v;  // 8 bf16 (4 VGPRs)
typedef __attribute__((ext_vector_type(4))) float f32x4;    // MFMA accum

// ---------------- Kernel 1: bf16-MFMA logits GEMM (validated round 3; unchanged)
#define BM 128
#define BN 128
#define BK 32

__global__ __launch_bounds__(256) void k_gemm(const float* __restrict__ x,
                                              const float* __restrict__ W,
                                              const float* __restrict__ bias,
                                              ushort* __restrict__ vb) {
    __shared__ ushort As[2][BM * BK];
    __shared__ ushort Bs[2][BN * BK];

    const int tid  = threadIdx.x;
    const int lane = tid & 63;
    const int w    = tid >> 6;          // wave 0..3
    const int wr   = w >> 1, wc = w & 1;
    const int m0   = blockIdx.y * BM;
    const int n0   = blockIdx.x * BN;

    const int srow = tid >> 1;
    const int skh  = (tid & 1) * 16;
    const float* xa = &x[(size_t)(m0 + srow) * D_ + skh];
    const float* wa = &W[(size_t)(n0 + srow) * D_ + skh];
    const int s0    = skh >> 3;
    const int wof0  = srow * 64 + (((s0 + 0) ^ (srow & 3)) << 4);
    const int wof1  = srow * 64 + (((s0 + 1) ^ (srow & 3)) << 4);

    const int slotsw = (((lane >> 4) ^ (lane & 3)) << 4);
    const int abase  = (wr * 64 + (lane & 15)) * 64 + slotsw;
    const int bbase  = (wc * 64 + (lane & 15)) * 64 + slotsw;

    f32x4 acc[4][4];
#pragma unroll
    for (int i = 0; i < 4; i++)
#pragma unroll
        for (int j = 0; j < 4; j++) acc[i][j] = (f32x4)(0.f);

    float4 ra[4], rb[4];
#pragma unroll
    for (int j = 0; j < 4; j++) {
        ra[j] = *(const float4*)&xa[j * 4];
        rb[j] = *(const float4*)&wa[j * 4];
    }

    auto pk = [](float a, float b) {
        return (__float_as_uint(a) >> 16) | (__float_as_uint(b) & 0xFFFF0000u);
    };

    for (int t = 0; t < D_ / BK; t++) {
        __syncthreads();
        uint4 pa0 = {pk(ra[0].x, ra[0].y), pk(ra[0].z, ra[0].w), pk(ra[1].x, ra[1].y), pk(ra[1].z, ra[1].w)};
        uint4 pa1 = {pk(ra[2].x, ra[2].y), pk(ra[2].z, ra[2].w), pk(ra[3].x, ra[3].y), pk(ra[3].z, ra[3].w)};
        uint4 pb0 = {pk(rb[0].x, rb[0].y), pk(rb[0].z, rb[0].w), pk(rb[1].x, rb[1].y), pk(rb[1].z, rb[1].w)};
        uint4 pb1 = {pk(rb[2].x, rb[2].y), pk(rb[2].z, rb[2].w), pk(rb[3].x, rb[3].y), pk(rb[3].z, rb[3].w)};
        char* Ab = (char*)As[t & 1];
        char* Bb = (char*)Bs[t & 1];
        *(uint4*)(Ab + wof0) = pa0;  *(uint4*)(Ab + wof1) = pa1;
        *(uint4*)(Bb + wof0) = pb0;  *(uint4*)(Bb + wof1) = pb1;
        if (t + 1 < D_ / BK) {
#pragma unroll
            for (int j = 0; j < 4; j++) {
                ra[j] = *(const float4*)&xa[(t + 1) * BK + j * 4];
                rb[j] = *(const float4*)&wa[(t + 1) * BK + j * 4];
            }
        }
        __syncthreads();
        const char* Ar = (const char*)As[t & 1];
        const char* Br = (const char*)Bs[t & 1];
        short8v af[4], bf[4];
#pragma unroll
        for (int mi = 0; mi < 4; mi++) af[mi] = *(const short8v*)(Ar + abase + mi * 16 * 64);
#pragma unroll
        for (int ni = 0; ni < 4; ni++) bf[ni] = *(const short8v*)(Br + bbase + ni * 16 * 64);
#pragma unroll
        for (int mi = 0; mi < 4; mi++)
#pragma unroll
            for (int ni = 0; ni < 4; ni++)
                acc[mi][ni] = __builtin_amdgcn_mfma_f32_16x16x32_bf16(af[mi], bf[ni], acc[mi][ni], 0, 0, 0);
    }

    // C/D layout (HW-verified): col = lane&15, row = (lane>>4)*4 + reg
#pragma unroll
    for (int ni = 0; ni < 4; ni++) {
        const int col = n0 + wc * 64 + ni * 16 + (lane & 15);
        const float bv = bias[col];
#pragma unroll
        for (int mi = 0; mi < 4; mi++) {
#pragma unroll
            for (int r = 0; r < 4; r++) {
                const int row = m0 + wr * 64 + mi * 16 + (lane >> 4) * 4 + r;
                vb[(size_t)row * NSLOT + col] = (ushort)(__float_as_uint(acc[mi][ni][r] + bv) >> 16);
            }
        }
    }
}

// ---------------- Kernel 2: top-2(bf16) -> margin threshold -> fp32 rescore -> top-2
// One (v1,v2) butterfly instead of 6 argmax passes; candidate set = all slots with
// bf16 > v2 - margin, margin >= 2 ulp (provably contains the fp32 top-2; truncation
// error per value < 1 ulp, ulp/|v| <= 2^-7).
__global__ __launch_bounds__(256) void k_sel(const ushort* __restrict__ vb,
                                             const float* __restrict__ x,
                                             const float* __restrict__ W,
                                             const float* __restrict__ bias,
                                             float* __restrict__ vals,
                                             int* __restrict__ cnt,
                                             int* __restrict__ list) {
    __shared__ int scnt[4];
    __shared__ int scand[4][MAXC];

    const int lane = threadIdx.x & 63;
    const int wv   = threadIdx.x >> 6;
    const int t    = blockIdx.x * 4 + wv;   // token id
    const int base = lane * 8;

    // bf16 logit row: one 16B load = 8 slots per lane
    uint4 c = *(const uint4*)(vb + (size_t)t * NSLOT + base);
    float lv[8];
    lv[0] = __uint_as_float((c.x & 0xFFFFu) << 16); lv[1] = __uint_as_float(c.x & 0xFFFF0000u);
    lv[2] = __uint_as_float((c.y & 0xFFFFu) << 16); lv[3] = __uint_as_float(c.y & 0xFFFF0000u);
    lv[4] = __uint_as_float((c.z & 0xFFFFu) << 16); lv[5] = __uint_as_float(c.z & 0xFFFF0000u);
    lv[6] = __uint_as_float((c.w & 0xFFFFu) << 16); lv[7] = __uint_as_float(c.w & 0xFFFF0000u);

    // exact bf16 (v1,v2) with index tie-break: per-lane then one butterfly
    float v1 = -INFINITY, v2 = -INFINITY;
    int   i1 = 1 << 30,   i2 = 1 << 30;
    auto ins = [&](float nv, int ni) {
        if (nv > v1 || (nv == v1 && ni < i1)) { v2 = v1; i2 = i1; v1 = nv; i1 = ni; }
        else if (nv > v2 || (nv == v2 && ni < i2)) { v2 = nv; i2 = ni; }
    };
#pragma unroll
    for (int j = 0; j < 8; j++) ins(lv[j], base + j);
#pragma unroll
    for (int m = 1; m < 64; m <<= 1) {
        float ov1 = __shfl_xor(v1, m, 64); int oi1 = __shfl_xor(i1, m, 64);
        float ov2 = __shfl_xor(v2, m, 64); int oi2 = __shfl_xor(i2, m, 64);
        ins(ov1, oi1); ins(ov2, oi2);
    }

    const float margin = fmaxf(0.04f, 0.016f * fabsf(v2));
    const float tau    = v2 - margin;

    if (lane == 0) scnt[wv] = 0;   // per-wave slot; same-wave LDS ops are ordered
#pragma unroll
    for (int j = 0; j < 8; j++) {
        if (lv[j] > tau) {
            int p = atomicAdd(&scnt[wv], 1);
            if (p < MAXC) scand[wv][p] = base + j;
        }
    }
    const int nC = min(scnt[wv], MAXC);   // >= 2 always (v1, v2 slots pass)

    // fp32 rescore: x row staged per lane (unit-stride coalesced), candidates in pairs
    float4 xv[4];
#pragma unroll
    for (int j = 0; j < 4; j++)
        xv[j] = *(const float4*)&x[(size_t)t * D_ + j * 256 + lane * 4];

    float fv1 = -INFINITY, fv2 = -INFINITY;
    int   fi1 = 1 << 30,   fi2 = 1 << 30;
    auto ins2 = [&](float nv, int ni) {
        if (nv > fv1 || (nv == fv1 && ni < fi1)) { fv2 = fv1; fi2 = fi1; fv1 = nv; fi1 = ni; }
        else if (nv > fv2 || (nv == fv2 && ni < fi2)) { fv2 = nv; fi2 = ni; }
    };
    for (int p0 = 0; p0 < nC; p0 += 2) {
        const bool two = (p0 + 1 < nC);
        const int ia = scand[wv][p0];
        const int ib = two ? scand[wv][p0 + 1] : ia;
        const float* wa = &W[(size_t)ia * D_];
        const float* wb = &W[(size_t)ib * D_];
        float da = 0.f, db = 0.f;
#pragma unroll
        for (int j = 0; j < 4; j++) {   // independent load streams -> ILP
            float4 av = *(const float4*)&wa[j * 256 + lane * 4];
            float4 bv = *(const float4*)&wb[j * 256 + lane * 4];
            da = fmaf(xv[j].x, av.x, da); da = fmaf(xv[j].y, av.y, da);
            da = fmaf(xv[j].z, av.z, da); da = fmaf(xv[j].w, av.w, da);
            db = fmaf(xv[j].x, bv.x, db); db = fmaf(xv[j].y, bv.y, db);
            db = fmaf(xv[j].z, bv.z, db); db = fmaf(xv[j].w, bv.w, db);
        }
#pragma unroll
        for (int m = 1; m < 64; m <<= 1) {   // fused 2-wide butterfly (one 6-deep chain)
            da += __shfl_xor(da, m, 64);
            db += __shfl_xor(db, m, 64);
        }
        ins2(da + bias[ia], ia);
        if (two) ins2(db + bias[ib], ib);
    }

    if (lane == 0) {
        vals[t * 2 + 0] = fv1;
        vals[t * 2 + 1] = fv2;
        const int b = t >> 11;
        const int l = t & (L_ - 1);
        int node = fi1 >> 3, head = fi1 & 7;
        int p = atomicAdd(&cnt[b * NN + node], 1);
        if (p < CAP) list[(size_t)(b * NN + node) * CAP + p] = (l << 4) | (head << 1) | 0;
        node = fi2 >> 3; head = fi2 & 7;
        p = atomicAdd(&cnt[b * NN + node], 1);
        if (p < CAP) list[(size_t)(b * NN + node) * CAP + p] = (l << 4) | (head << 1) | 1;
    }
}

// ---------------- Kernel 3: per-(b,node) gather-reduce, 4-way unrolled for MLP
__global__ __launch_bounds__(256) void k_scatter(const float* __restrict__ x,
                                                 const float* __restrict__ gv,
                                                 const float* __restrict__ vals,
                                                 const int* __restrict__ cnt,
                                                 const int* __restrict__ list,
                                                 float* __restrict__ out) {
    const int bn   = blockIdx.x;          // b*64 + node
    const int b    = bn >> 6;
    const int node = bn & 63;
    const int tid  = threadIdx.x;
    const int raw  = cnt[bn];
    const int n    = min(raw, CAP);

    __shared__ int   se[CAP];
    __shared__ float sv[CAP];
    __shared__ float sg[NH][D_];          // 32 KiB

    for (int i = tid; i < NH * D_; i += 256)
        sg[i >> 10][i & (D_ - 1)] = gv[((size_t)node << 13) + i];
    for (int i = tid; i < n; i += 256) {
        int e = list[(size_t)bn * CAP + i];
        se[i] = e;
        sv[i] = vals[(size_t)(((b << 11) | (e >> 4)) * 2 + (e & 1))];
    }
    __syncthreads();

    const int d = tid * 4;
    float ax = 0.f, ay = 0.f, az = 0.f, aw = 0.f;
    int i = 0;
    for (; i + 4 <= n; i += 4) {          // 4 gathers in flight per wave
        const int e0 = se[i], e1 = se[i+1], e2 = se[i+2], e3 = se[i+3];
        const float w0 = sv[i], w1 = sv[i+1], w2 = sv[i+2], w3 = sv[i+3];
        float4 x0 = *(const float4*)&x[(size_t)(((b << 11) | (e0 >> 4)) << 10) + d];
        float4 x1 = *(const float4*)&x[(size_t)(((b << 11) | (e1 >> 4)) << 10) + d];
        float4 x2 = *(const float4*)&x[(size_t)(((b << 11) | (e2 >> 4)) << 10) + d];
        float4 x3 = *(const float4*)&x[(size_t)(((b << 11) | (e3 >> 4)) << 10) + d];
        float4 g0 = *(const float4*)&sg[(e0 >> 1) & 7][d];
        float4 g1 = *(const float4*)&sg[(e1 >> 1) & 7][d];
        float4 g2 = *(const float4*)&sg[(e2 >> 1) & 7][d];
        float4 g3 = *(const float4*)&sg[(e3 >> 1) & 7][d];
        ax = fmaf(w0 * x0.x, g0.x, ax); ay = fmaf(w0 * x0.y, g0.y, ay);
        az = fmaf(w0 * x0.z, g0.z, az); aw = fmaf(w0 * x0.w, g0.w, aw);
        ax = fmaf(w1 * x1.x, g1.x, ax); ay = fmaf(w1 * x1.y, g1.y, ay);
        az = fmaf(w1 * x1.z, g1.z, az); aw = fmaf(w1 * x1.w, g1.w, aw);
        ax = fmaf(w2 * x2.x, g2.x, ax); ay = fmaf(w2 * x2.y, g2.y, ay);
        az = fmaf(w2 * x2.z, g2.z, az); aw = fmaf(w2 * x2.w, g2.w, aw);
        ax = fmaf(w3 * x3.x, g3.x, ax); ay = fmaf(w3 * x3.y, g3.y, ay);
        az = fmaf(w3 * x3.z, g3.z, az); aw = fmaf(w3 * x3.w, g3.w, aw);
    }
    for (; i < n; i++) {
        const int e = se[i];
        const float vv = sv[i];
        float4 xv = *(const float4*)&x[(size_t)(((b << 11) | (e >> 4)) << 10) + d];
        float4 gh = *(const float4*)&sg[(e >> 1) & 7][d];
        ax = fmaf(vv * xv.x, gh.x, ax); ay = fmaf(vv * xv.y, gh.y, ay);
        az = fmaf(vv * xv.z, gh.z, az); aw = fmaf(vv * xv.w, gh.w, aw);
    }
    float4 o = {ax, ay, az, aw};
    *(float4*)&out[((size_t)bn << 10) + d] = o;
    if (tid == 0) out[(size_t)B_ * NN * D_ + bn] = (float)raw;
}

extern "C" void kernel_launch(void* const* d_in, const int* in_sizes, int n_in,
                              void* d_out, int out_size, void* d_ws, size_t ws_size,
                              hipStream_t stream) {
    (void)in_sizes; (void)n_in; (void)out_size; (void)ws_size;
    const float* x    = (const float*)d_in[0];
    const float* W    = (const float*)d_in[1];
    const float* bias = (const float*)d_in[2];
    const float* gv   = (const float*)d_in[3];
    float* out = (float*)d_out;

    // workspace layout (~18.2 MiB)
    ushort* vb  = (ushort*)d_ws;                       // 16384*512 bf16 = 16 MiB
    float* vals = (float*)(vb + (size_t)NTOK * NSLOT); // 32768 f32
    int*   cnt  = (int*)(vals + (size_t)NTOK * 2);     // 512 i32
    int*   list = cnt + B_ * NN;                       // 512*CAP i32 = 2 MiB

    hipMemsetAsync(cnt, 0, B_ * NN * sizeof(int), stream);

    dim3 g1(NSLOT / BN, NTOK / BM);                    // (4, 128)
    k_gemm<<<g1, 256, 0, stream>>>(x, W, bias, vb);
    k_sel<<<NTOK / 4, 256, 0, stream>>>(vb, x, W, bias, vals, cnt, list);
    k_scatter<<<B_ * NN, 256, 0, stream>>>(x, gv, vals, cnt, list, out);
}

// Round 5
// 245.850 us; speedup vs baseline: 1.1104x; 1.1104x over previous
//
#include <hip/hip_runtime.h>
#include <math.h>

// Problem constants (match reference)
#define B_    8
#define L_    2048
#define D_    1024
#define NN    64        // NUM_NODES
#define NH    8         // NUM_HEADS
#define NSLOT 512       // NN*NH
#define NTOK  (B_*L_)   // 16384
#define CAP   1024      // per-(b,node) match capacity (mean 64, binom std ~8)
#define MAXC  8         // max rescore candidates (margin window holds 2-4 typ.)

typedef __attribute__((ext_vector_type(8))) short short8v;  // 8 bf16 (4 VGPRs)
typedef __attribute__((ext_vector_type(4))) float f32x4;    // MFMA accum

// ---------------- Kernel 1: bf16-MFMA logits GEMM (validated r3/r4; unchanged)
#define BM 128
#define BN 128
#define BK 32

__global__ __launch_bounds__(256) void k_gemm(const float* __restrict__ x,
                                              const float* __restrict__ W,
                                              const float* __restrict__ bias,
                                              ushort* __restrict__ vb) {
    __shared__ ushort As[2][BM * BK];
    __shared__ ushort Bs[2][BN * BK];

    const int tid  = threadIdx.x;
    const int lane = tid & 63;
    const int w    = tid >> 6;          // wave 0..3
    const int wr   = w >> 1, wc = w & 1;
    const int m0   = blockIdx.y * BM;
    const int n0   = blockIdx.x * BN;

    const int srow = tid >> 1;
    const int skh  = (tid & 1) * 16;
    const float* xa = &x[(size_t)(m0 + srow) * D_ + skh];
    const float* wa = &W[(size_t)(n0 + srow) * D_ + skh];
    const int s0    = skh >> 3;
    const int wof0  = srow * 64 + (((s0 + 0) ^ (srow & 3)) << 4);
    const int wof1  = srow * 64 + (((s0 + 1) ^ (srow & 3)) << 4);

    const int slotsw = (((lane >> 4) ^ (lane & 3)) << 4);
    const int abase  = (wr * 64 + (lane & 15)) * 64 + slotsw;
    const int bbase  = (wc * 64 + (lane & 15)) * 64 + slotsw;

    f32x4 acc[4][4];
#pragma unroll
    for (int i = 0; i < 4; i++)
#pragma unroll
        for (int j = 0; j < 4; j++) acc[i][j] = (f32x4)(0.f);

    float4 ra[4], rb[4];
#pragma unroll
    for (int j = 0; j < 4; j++) {
        ra[j] = *(const float4*)&xa[j * 4];
        rb[j] = *(const float4*)&wa[j * 4];
    }

    auto pk = [](float a, float b) {
        return (__float_as_uint(a) >> 16) | (__float_as_uint(b) & 0xFFFF0000u);
    };

    for (int t = 0; t < D_ / BK; t++) {
        __syncthreads();
        uint4 pa0 = {pk(ra[0].x, ra[0].y), pk(ra[0].z, ra[0].w), pk(ra[1].x, ra[1].y), pk(ra[1].z, ra[1].w)};
        uint4 pa1 = {pk(ra[2].x, ra[2].y), pk(ra[2].z, ra[2].w), pk(ra[3].x, ra[3].y), pk(ra[3].z, ra[3].w)};
        uint4 pb0 = {pk(rb[0].x, rb[0].y), pk(rb[0].z, rb[0].w), pk(rb[1].x, rb[1].y), pk(rb[1].z, rb[1].w)};
        uint4 pb1 = {pk(rb[2].x, rb[2].y), pk(rb[2].z, rb[2].w), pk(rb[3].x, rb[3].y), pk(rb[3].z, rb[3].w)};
        char* Ab = (char*)As[t & 1];
        char* Bb = (char*)Bs[t & 1];
        *(uint4*)(Ab + wof0) = pa0;  *(uint4*)(Ab + wof1) = pa1;
        *(uint4*)(Bb + wof0) = pb0;  *(uint4*)(Bb + wof1) = pb1;
        if (t + 1 < D_ / BK) {
#pragma unroll
            for (int j = 0; j < 4; j++) {
                ra[j] = *(const float4*)&xa[(t + 1) * BK + j * 4];
                rb[j] = *(const float4*)&wa[(t + 1) * BK + j * 4];
            }
        }
        __syncthreads();
        const char* Ar = (const char*)As[t & 1];
        const char* Br = (const char*)Bs[t & 1];
        short8v af[4], bf[4];
#pragma unroll
        for (int mi = 0; mi < 4; mi++) af[mi] = *(const short8v*)(Ar + abase + mi * 16 * 64);
#pragma unroll
        for (int ni = 0; ni < 4; ni++) bf[ni] = *(const short8v*)(Br + bbase + ni * 16 * 64);
#pragma unroll
        for (int mi = 0; mi < 4; mi++)
#pragma unroll
            for (int ni = 0; ni < 4; ni++)
                acc[mi][ni] = __builtin_amdgcn_mfma_f32_16x16x32_bf16(af[mi], bf[ni], acc[mi][ni], 0, 0, 0);
    }

    // C/D layout (HW-verified): col = lane&15, row = (lane>>4)*4 + reg
#pragma unroll
    for (int ni = 0; ni < 4; ni++) {
        const int col = n0 + wc * 64 + ni * 16 + (lane & 15);
        const float bv = bias[col];
#pragma unroll
        for (int mi = 0; mi < 4; mi++) {
#pragma unroll
            for (int r = 0; r < 4; r++) {
                const int row = m0 + wr * 64 + mi * 16 + (lane >> 4) * 4 + r;
                vb[(size_t)row * NSLOT + col] = (ushort)(__float_as_uint(acc[mi][ni][r] + bv) >> 16);
            }
        }
    }
}

// ---------------- Kernel 2: top-2(bf16) -> margin threshold -> fp32 rescore -> top-2
// NO global atomics: emits one coalesced 16B record per token:
//   sel[t] = { i1, i2, bits(v1), bits(v2) }
__global__ __launch_bounds__(256) void k_sel(const ushort* __restrict__ vb,
                                             const float* __restrict__ x,
                                             const float* __restrict__ W,
                                             const float* __restrict__ bias,
                                             uint* __restrict__ sel) {
    __shared__ int scnt[4];
    __shared__ int scand[4][MAXC];

    const int lane = threadIdx.x & 63;
    const int wv   = threadIdx.x >> 6;
    const int t    = blockIdx.x * 4 + wv;   // token id
    const int base = lane * 8;

    // bf16 logit row: one 16B load = 8 slots per lane
    uint4 c = *(const uint4*)(vb + (size_t)t * NSLOT + base);
    float lv[8];
    lv[0] = __uint_as_float((c.x & 0xFFFFu) << 16); lv[1] = __uint_as_float(c.x & 0xFFFF0000u);
    lv[2] = __uint_as_float((c.y & 0xFFFFu) << 16); lv[3] = __uint_as_float(c.y & 0xFFFF0000u);
    lv[4] = __uint_as_float((c.z & 0xFFFFu) << 16); lv[5] = __uint_as_float(c.z & 0xFFFF0000u);
    lv[6] = __uint_as_float((c.w & 0xFFFFu) << 16); lv[7] = __uint_as_float(c.w & 0xFFFF0000u);

    // exact bf16 (v1,v2) with index tie-break: per-lane then one butterfly
    float v1 = -INFINITY, v2 = -INFINITY;
    int   i1 = 1 << 30,   i2 = 1 << 30;
    auto ins = [&](float nv, int ni) {
        if (nv > v1 || (nv == v1 && ni < i1)) { v2 = v1; i2 = i1; v1 = nv; i1 = ni; }
        else if (nv > v2 || (nv == v2 && ni < i2)) { v2 = nv; i2 = ni; }
    };
#pragma unroll
    for (int j = 0; j < 8; j++) ins(lv[j], base + j);
#pragma unroll
    for (int m = 1; m < 64; m <<= 1) {
        float ov1 = __shfl_xor(v1, m, 64); int oi1 = __shfl_xor(i1, m, 64);
        float ov2 = __shfl_xor(v2, m, 64); int oi2 = __shfl_xor(i2, m, 64);
        ins(ov1, oi1); ins(ov2, oi2);
    }

    // margin >= 2 ulp(bf16) guarantees the fp32 top-2 slots are in the window
    const float margin = fmaxf(0.04f, 0.016f * fabsf(v2));
    const float tau    = v2 - margin;

    if (lane == 0) scnt[wv] = 0;   // per-wave slot; same-wave LDS ops are ordered
#pragma unroll
    for (int j = 0; j < 8; j++) {
        if (lv[j] > tau) {
            int p = atomicAdd(&scnt[wv], 1);      // LDS atomic (cheap)
            if (p < MAXC) scand[wv][p] = base + j;
        }
    }
    const int nC = min(scnt[wv], MAXC);   // >= 2 always (v1, v2 slots pass)

    // fp32 rescore: x row staged per lane, candidates in pairs for load ILP
    float4 xv[4];
#pragma unroll
    for (int j = 0; j < 4; j++)
        xv[j] = *(const float4*)&x[(size_t)t * D_ + j * 256 + lane * 4];

    float fv1 = -INFINITY, fv2 = -INFINITY;
    int   fi1 = 1 << 30,   fi2 = 1 << 30;
    auto ins2 = [&](float nv, int ni) {
        if (nv > fv1 || (nv == fv1 && ni < fi1)) { fv2 = fv1; fi2 = fi1; fv1 = nv; fi1 = ni; }
        else if (nv > fv2 || (nv == fv2 && ni < fi2)) { fv2 = nv; fi2 = ni; }
    };
    for (int p0 = 0; p0 < nC; p0 += 2) {
        const bool two = (p0 + 1 < nC);
        const int ia = scand[wv][p0];
        const int ib = two ? scand[wv][p0 + 1] : ia;
        const float* wa = &W[(size_t)ia * D_];
        const float* wb = &W[(size_t)ib * D_];
        float da = 0.f, db = 0.f;
#pragma unroll
        for (int j = 0; j < 4; j++) {   // independent load streams -> ILP
            float4 av = *(const float4*)&wa[j * 256 + lane * 4];
            float4 bv = *(const float4*)&wb[j * 256 + lane * 4];
            da = fmaf(xv[j].x, av.x, da); da = fmaf(xv[j].y, av.y, da);
            da = fmaf(xv[j].z, av.z, da); da = fmaf(xv[j].w, av.w, da);
            db = fmaf(xv[j].x, bv.x, db); db = fmaf(xv[j].y, bv.y, db);
            db = fmaf(xv[j].z, bv.z, db); db = fmaf(xv[j].w, bv.w, db);
        }
#pragma unroll
        for (int m = 1; m < 64; m <<= 1) {   // fused 2-wide butterfly
            da += __shfl_xor(da, m, 64);
            db += __shfl_xor(db, m, 64);
        }
        ins2(da + bias[ia], ia);
        if (two) ins2(db + bias[ib], ib);
    }

    if (lane == 0) {
        uint4 s;
        s.x = (uint)fi1;
        s.y = (uint)fi2;
        s.z = __float_as_uint(fv1);
        s.w = __float_as_uint(fv2);
        *(uint4*)&sel[(size_t)t * 4] = s;
    }
}

// ---------------- Kernel 3: per-(b,node) scan + compact + gather-reduce
// Each block scans its batch's sel[] (32 KB, L2-shared by the 64 node-blocks of
// that batch), compacts matches via LDS atomics, then 4-way-unrolled gather-FMA.
__global__ __launch_bounds__(256) void k_scatter(const float* __restrict__ x,
                                                 const float* __restrict__ gv,
                                                 const uint* __restrict__ sel,
                                                 float* __restrict__ out) {
    const int bn   = blockIdx.x;          // b*64 + node
    const int b    = bn >> 6;
    const int node = bn & 63;
    const int tid  = threadIdx.x;

    __shared__ int   se[CAP];             // (l<<3)|head
    __shared__ float sv[CAP];
    __shared__ float sg[NH][D_];          // 32 KiB
    __shared__ int   scnt;

    if (tid == 0) scnt = 0;
    for (int i = tid; i < NH * D_; i += 256)
        sg[i >> 10][i & (D_ - 1)] = gv[((size_t)node << 13) + i];
    __syncthreads();                      // scnt=0 + gates visible

    // scan this batch's 2048 sel records; push matches (order-independent sum)
    for (int i = tid; i < L_; i += 256) {
        uint4 s = *(const uint4*)&sel[(size_t)((b << 11) | i) * 4];
        if ((int)(s.x >> 3) == node) {
            int p = atomicAdd(&scnt, 1);
            if (p < CAP) { se[p] = (i << 3) | (s.x & 7); sv[p] = __uint_as_float(s.z); }
        }
        if ((int)(s.y >> 3) == node) {
            int p = atomicAdd(&scnt, 1);
            if (p < CAP) { se[p] = (i << 3) | (s.y & 7); sv[p] = __uint_as_float(s.w); }
        }
    }
    __syncthreads();
    const int raw = scnt;
    const int n   = min(raw, CAP);

    const int d = tid * 4;
    float ax = 0.f, ay = 0.f, az = 0.f, aw = 0.f;
    int i = 0;
    for (; i + 4 <= n; i += 4) {          // 4 gathers in flight per wave
        const int e0 = se[i], e1 = se[i+1], e2 = se[i+2], e3 = se[i+3];
        const float w0 = sv[i], w1 = sv[i+1], w2 = sv[i+2], w3 = sv[i+3];
        float4 x0 = *(const float4*)&x[(size_t)(((b << 11) | (e0 >> 3)) << 10) + d];
        float4 x1 = *(const float4*)&x[(size_t)(((b << 11) | (e1 >> 3)) << 10) + d];
        float4 x2 = *(const float4*)&x[(size_t)(((b << 11) | (e2 >> 3)) << 10) + d];
        float4 x3 = *(const float4*)&x[(size_t)(((b << 11) | (e3 >> 3)) << 10) + d];
        float4 g0 = *(const float4*)&sg[e0 & 7][d];
        float4 g1 = *(const float4*)&sg[e1 & 7][d];
        float4 g2 = *(const float4*)&sg[e2 & 7][d];
        float4 g3 = *(const float4*)&sg[e3 & 7][d];
        ax = fmaf(w0 * x0.x, g0.x, ax); ay = fmaf(w0 * x0.y, g0.y, ay);
        az = fmaf(w0 * x0.z, g0.z, az); aw = fmaf(w0 * x0.w, g0.w, aw);
        ax = fmaf(w1 * x1.x, g1.x, ax); ay = fmaf(w1 * x1.y, g1.y, ay);
        az = fmaf(w1 * x1.z, g1.z, az); aw = fmaf(w1 * x1.w, g1.w, aw);
        ax = fmaf(w2 * x2.x, g2.x, ax); ay = fmaf(w2 * x2.y, g2.y, ay);
        az = fmaf(w2 * x2.z, g2.z, az); aw = fmaf(w2 * x2.w, g2.w, aw);
        ax = fmaf(w3 * x3.x, g3.x, ax); ay = fmaf(w3 * x3.y, g3.y, ay);
        az = fmaf(w3 * x3.z, g3.z, az); aw = fmaf(w3 * x3.w, g3.w, aw);
    }
    for (; i < n; i++) {
        const int e = se[i];
        const float vv = sv[i];
        float4 xv = *(const float4*)&x[(size_t)(((b << 11) | (e >> 3)) << 10) + d];
        float4 gh = *(const float4*)&sg[e & 7][d];
        ax = fmaf(vv * xv.x, gh.x, ax); ay = fmaf(vv * xv.y, gh.y, ay);
        az = fmaf(vv * xv.z, gh.z, az); aw = fmaf(vv * xv.w, gh.w, aw);
    }
    float4 o = {ax, ay, az, aw};
    *(float4*)&out[((size_t)bn << 10) + d] = o;
    if (tid == 0) out[(size_t)B_ * NN * D_ + bn] = (float)raw;   // uncapped count
}

extern "C" void kernel_launch(void* const* d_in, const int* in_sizes, int n_in,
                              void* d_out, int out_size, void* d_ws, size_t ws_size,
                              hipStream_t stream) {
    (void)in_sizes; (void)n_in; (void)out_size; (void)ws_size;
    const float* x    = (const float*)d_in[0];
    const float* W    = (const float*)d_in[1];
    const float* bias = (const float*)d_in[2];
    const float* gv   = (const float*)d_in[3];
    float* out = (float*)d_out;

    // workspace layout (~16.3 MiB)
    ushort* vb = (ushort*)d_ws;                        // 16384*512 bf16 = 16 MiB
    uint*   sel = (uint*)(vb + (size_t)NTOK * NSLOT);  // 16384*4 u32 = 256 KiB

    dim3 g1(NSLOT / BN, NTOK / BM);                    // (4, 128)
    k_gemm<<<g1, 256, 0, stream>>>(x, W, bias, vb);
    k_sel<<<NTOK / 4, 256, 0, stream>>>(vb, x, W, bias, sel);
    k_scatter<<<B_ * NN, 256, 0, stream>>>(x, gv, sel, out);
}

// Round 6
// 194.699 us; speedup vs baseline: 1.4022x; 1.2627x over previous
//
#include <hip/hip_runtime.h>
#include <math.h>

// Problem constants (match reference)
#define B_    8
#define L_    2048
#define D_    1024
#define NN    64        // NUM_NODES
#define NH    8         // NUM_HEADS
#define NSLOT 512       // NN*NH
#define NTOK  (B_*L_)   // 16384
#define CAP   1024      // per-(b,node) match capacity (mean 64, binom std ~8)
#define MAXC  8         // max rescore candidates (margin window holds 2-4 typ.)

typedef __attribute__((ext_vector_type(8))) short short8v;  // 8 bf16 (4 VGPRs)
typedef __attribute__((ext_vector_type(4))) float f32x4;    // MFMA accum

__device__ __forceinline__ uint umaxu(uint a, uint b) { return a > b ? a : b; }
__device__ __forceinline__ uint uminu(uint a, uint b) { return a < b ? a : b; }

// ---------------- Kernel 1: bf16-MFMA logits GEMM (validated r3-r5; unchanged)
#define BM 128
#define BN 128
#define BK 32

__global__ __launch_bounds__(256) void k_gemm(const float* __restrict__ x,
                                              const float* __restrict__ W,
                                              const float* __restrict__ bias,
                                              ushort* __restrict__ vb) {
    __shared__ ushort As[2][BM * BK];
    __shared__ ushort Bs[2][BN * BK];

    const int tid  = threadIdx.x;
    const int lane = tid & 63;
    const int w    = tid >> 6;          // wave 0..3
    const int wr   = w >> 1, wc = w & 1;
    const int m0   = blockIdx.y * BM;
    const int n0   = blockIdx.x * BN;

    const int srow = tid >> 1;
    const int skh  = (tid & 1) * 16;
    const float* xa = &x[(size_t)(m0 + srow) * D_ + skh];
    const float* wa = &W[(size_t)(n0 + srow) * D_ + skh];
    const int s0    = skh >> 3;
    const int wof0  = srow * 64 + (((s0 + 0) ^ (srow & 3)) << 4);
    const int wof1  = srow * 64 + (((s0 + 1) ^ (srow & 3)) << 4);

    const int slotsw = (((lane >> 4) ^ (lane & 3)) << 4);
    const int abase  = (wr * 64 + (lane & 15)) * 64 + slotsw;
    const int bbase  = (wc * 64 + (lane & 15)) * 64 + slotsw;

    f32x4 acc[4][4];
#pragma unroll
    for (int i = 0; i < 4; i++)
#pragma unroll
        for (int j = 0; j < 4; j++) acc[i][j] = (f32x4)(0.f);

    float4 ra[4], rb[4];
#pragma unroll
    for (int j = 0; j < 4; j++) {
        ra[j] = *(const float4*)&xa[j * 4];
        rb[j] = *(const float4*)&wa[j * 4];
    }

    auto pk = [](float a, float b) {
        return (__float_as_uint(a) >> 16) | (__float_as_uint(b) & 0xFFFF0000u);
    };

    for (int t = 0; t < D_ / BK; t++) {
        __syncthreads();
        uint4 pa0 = {pk(ra[0].x, ra[0].y), pk(ra[0].z, ra[0].w), pk(ra[1].x, ra[1].y), pk(ra[1].z, ra[1].w)};
        uint4 pa1 = {pk(ra[2].x, ra[2].y), pk(ra[2].z, ra[2].w), pk(ra[3].x, ra[3].y), pk(ra[3].z, ra[3].w)};
        uint4 pb0 = {pk(rb[0].x, rb[0].y), pk(rb[0].z, rb[0].w), pk(rb[1].x, rb[1].y), pk(rb[1].z, rb[1].w)};
        uint4 pb1 = {pk(rb[2].x, rb[2].y), pk(rb[2].z, rb[2].w), pk(rb[3].x, rb[3].y), pk(rb[3].z, rb[3].w)};
        char* Ab = (char*)As[t & 1];
        char* Bb = (char*)Bs[t & 1];
        *(uint4*)(Ab + wof0) = pa0;  *(uint4*)(Ab + wof1) = pa1;
        *(uint4*)(Bb + wof0) = pb0;  *(uint4*)(Bb + wof1) = pb1;
        if (t + 1 < D_ / BK) {
#pragma unroll
            for (int j = 0; j < 4; j++) {
                ra[j] = *(const float4*)&xa[(t + 1) * BK + j * 4];
                rb[j] = *(const float4*)&wa[(t + 1) * BK + j * 4];
            }
        }
        __syncthreads();
        const char* Ar = (const char*)As[t & 1];
        const char* Br = (const char*)Bs[t & 1];
        short8v af[4], bf[4];
#pragma unroll
        for (int mi = 0; mi < 4; mi++) af[mi] = *(const short8v*)(Ar + abase + mi * 16 * 64);
#pragma unroll
        for (int ni = 0; ni < 4; ni++) bf[ni] = *(const short8v*)(Br + bbase + ni * 16 * 64);
#pragma unroll
        for (int mi = 0; mi < 4; mi++)
#pragma unroll
            for (int ni = 0; ni < 4; ni++)
                acc[mi][ni] = __builtin_amdgcn_mfma_f32_16x16x32_bf16(af[mi], bf[ni], acc[mi][ni], 0, 0, 0);
    }

    // C/D layout (HW-verified): col = lane&15, row = (lane>>4)*4 + reg
#pragma unroll
    for (int ni = 0; ni < 4; ni++) {
        const int col = n0 + wc * 64 + ni * 16 + (lane & 15);
        const float bv = bias[col];
#pragma unroll
        for (int mi = 0; mi < 4; mi++) {
#pragma unroll
            for (int r = 0; r < 4; r++) {
                const int row = m0 + wr * 64 + mi * 16 + (lane >> 4) * 4 + r;
                vb[(size_t)row * NSLOT + col] = (ushort)(__float_as_uint(acc[mi][ni][r] + bv) >> 16);
            }
        }
    }
}

// ---------------- Kernel 2 (v4): 2 tokens/wave, packed-key scan, ballot compaction
// Per 32-lane group: bf16 top-2 via monotone-key tournament + 5-step butterfly,
// margin tau, ballot-prefix candidate compaction, exact fp32 rescore, ins2 top-2.
// sel[t] = { i1, i2, bits(v1), bits(v2) } -- no global atomics.
__global__ __launch_bounds__(256) void k_sel(const ushort* __restrict__ vb,
                                             const float* __restrict__ x,
                                             const float* __restrict__ W,
                                             const float* __restrict__ bias,
                                             uint* __restrict__ sel) {
    __shared__ int scand[8][MAXC];

    const int tid   = threadIdx.x;
    const int lane  = tid & 31;          // lane within 32-group
    const int grp   = tid >> 5;          // 0..7 token-group within block
    const int shift = (grp & 1) * 32;    // this group's half of the 64-bit ballot
    const int t     = blockIdx.x * 8 + grp;

    // vb row first (needed first), then x-row prefetch (used only at rescore;
    // its ~900cy HBM latency hides under the whole scan phase)
    const uint4 c0 = *(const uint4*)(vb + (size_t)t * NSLOT + lane * 16);
    const uint4 c1 = *(const uint4*)(vb + (size_t)t * NSLOT + lane * 16 + 8);
    float4 xv[8];
#pragma unroll
    for (int j = 0; j < 8; j++)
        xv[j] = *(const float4*)&x[(size_t)t * D_ + j * 128 + lane * 4];

    // unpack 16 bf16 -> float + monotone key (value-major, lowest-slot-major)
    const uint u[8] = {c0.x, c0.y, c0.z, c0.w, c1.x, c1.y, c1.z, c1.w};
    float lv[16];
    uint  key[16];
#pragma unroll
    for (int h = 0; h < 8; h++) {
        const uint rl = u[h] & 0xFFFFu, rh = u[h] >> 16;
        lv[2*h]   = __uint_as_float(u[h] << 16);
        lv[2*h+1] = __uint_as_float(u[h] & 0xFFFF0000u);
        const uint ml = rl ^ ((rl & 0x8000u) ? 0xFFFFu : 0x8000u);
        const uint mh = rh ^ ((rh & 0x8000u) ? 0xFFFFu : 0x8000u);
        key[2*h]   = (ml << 9) | (511u - (uint)(lane * 16 + 2*h));
        key[2*h+1] = (mh << 9) | (511u - (uint)(lane * 16 + 2*h + 1));
    }

    // per-lane top-2 keys: pairwise + 3-level merge tree (keys unique -> no ties)
    auto mrg = [](uint& a1, uint& a2, uint b1, uint b2) {
        const uint m1 = umaxu(a1, b1);
        const uint m2 = (a1 > b1) ? umaxu(a2, b1) : umaxu(b2, a1);
        a1 = m1; a2 = m2;
    };
    uint h1[8], l1[8];
#pragma unroll
    for (int i = 0; i < 8; i++) {
        h1[i] = umaxu(key[2*i], key[2*i+1]);
        l1[i] = uminu(key[2*i], key[2*i+1]);
    }
#pragma unroll
    for (int i = 0; i < 4; i++) mrg(h1[i], l1[i], h1[i+4], l1[i+4]);
#pragma unroll
    for (int i = 0; i < 2; i++) mrg(h1[i], l1[i], h1[i+2], l1[i+2]);
    mrg(h1[0], l1[0], h1[1], l1[1]);
    uint k1 = h1[0], k2 = l1[0];

    // 5-step butterfly within the 32-group (one instruction serves both groups)
#pragma unroll
    for (int m = 1; m < 32; m <<= 1) {
        const uint o1 = (uint)__shfl_xor((int)k1, m, 64);
        const uint o2 = (uint)__shfl_xor((int)k2, m, 64);
        mrg(k1, k2, o1, o2);
    }

    // decode v2 (bf16) -> float; tau with margin >= 2 ulp(bf16)
    const uint m2b = k2 >> 9;
    const uint r2  = (m2b >= 0x8000u) ? (m2b ^ 0x8000u) : (m2b ^ 0xFFFFu);
    const float v2f = __uint_as_float(r2 << 16);
    const float tau = v2f - fmaxf(0.04f, 0.016f * fabsf(v2f));

    // ballot-prefix compaction of candidates (no LDS atomics)
    uint off = 0;
#pragma unroll
    for (int j = 0; j < 16; j++) {
        const bool p = lv[j] > tau;
        const unsigned long long bal = __ballot(p);
        const uint gm = (uint)(bal >> shift);
        if (p) {
            const uint pos = off + (uint)__popc(gm & ((1u << lane) - 1u));
            if (pos < MAXC) scand[grp][pos] = lane * 16 + j;
        }
        off += (uint)__popc(gm);
    }
    const int nC = min((int)off, MAXC);   // >= 2 always (v1, v2 slots pass)

    // exact fp32 rescore (same validated logic/order as r4/r5)
    float fv1 = -INFINITY, fv2 = -INFINITY;
    int   fi1 = 1 << 30,   fi2 = 1 << 30;
    auto ins2 = [&](float nv, int ni) {
        if (nv > fv1 || (nv == fv1 && ni < fi1)) { fv2 = fv1; fi2 = fi1; fv1 = nv; fi1 = ni; }
        else if (nv > fv2 || (nv == fv2 && ni < fi2)) { fv2 = nv; fi2 = ni; }
    };
    for (int p0 = 0; p0 < nC; p0 += 2) {
        const bool two = (p0 + 1 < nC);
        const int ia = scand[grp][p0];
        const int ib = two ? scand[grp][p0 + 1] : ia;
        const float* wa = &W[(size_t)ia * D_];
        const float* wb = &W[(size_t)ib * D_];
        float da0 = 0.f, da1 = 0.f, db0 = 0.f, db1 = 0.f;
#pragma unroll
        for (int j = 0; j < 8; j++) {     // dual rows + dual accumulators -> ILP
            const float4 av = *(const float4*)&wa[j * 128 + lane * 4];
            const float4 bv = *(const float4*)&wb[j * 128 + lane * 4];
            const float4 xj = xv[j];
            if (j & 1) {
                da1 = fmaf(xj.x, av.x, da1); da1 = fmaf(xj.y, av.y, da1);
                da1 = fmaf(xj.z, av.z, da1); da1 = fmaf(xj.w, av.w, da1);
                db1 = fmaf(xj.x, bv.x, db1); db1 = fmaf(xj.y, bv.y, db1);
                db1 = fmaf(xj.z, bv.z, db1); db1 = fmaf(xj.w, bv.w, db1);
            } else {
                da0 = fmaf(xj.x, av.x, da0); da0 = fmaf(xj.y, av.y, da0);
                da0 = fmaf(xj.z, av.z, da0); da0 = fmaf(xj.w, av.w, da0);
                db0 = fmaf(xj.x, bv.x, db0); db0 = fmaf(xj.y, bv.y, db0);
                db0 = fmaf(xj.z, bv.z, db0); db0 = fmaf(xj.w, bv.w, db0);
            }
        }
        float da = da0 + da1, db = db0 + db1;
#pragma unroll
        for (int m = 1; m < 32; m <<= 1) {
            da += __shfl_xor(da, m, 64);
            db += __shfl_xor(db, m, 64);
        }
        ins2(da + bias[ia], ia);
        if (two) ins2(db + bias[ib], ib);
    }

    if (lane == 0) {
        uint4 s;
        s.x = (uint)fi1;
        s.y = (uint)fi2;
        s.z = __float_as_uint(fv1);
        s.w = __float_as_uint(fv2);
        *(uint4*)&sel[(size_t)t * 4] = s;
    }
}

// ---------------- Kernel 3: per-(b,node) scan + compact + gather-reduce (r5; unchanged)
__global__ __launch_bounds__(256) void k_scatter(const float* __restrict__ x,
                                                 const float* __restrict__ gv,
                                                 const uint* __restrict__ sel,
                                                 float* __restrict__ out) {
    const int bn   = blockIdx.x;          // b*64 + node
    const int b    = bn >> 6;
    const int node = bn & 63;
    const int tid  = threadIdx.x;

    __shared__ int   se[CAP];             // (l<<3)|head
    __shared__ float sv[CAP];
    __shared__ float sg[NH][D_];          // 32 KiB
    __shared__ int   scnt;

    if (tid == 0) scnt = 0;
    for (int i = tid; i < NH * D_; i += 256)
        sg[i >> 10][i & (D_ - 1)] = gv[((size_t)node << 13) + i];
    __syncthreads();                      // scnt=0 + gates visible

    for (int i = tid; i < L_; i += 256) {
        uint4 s = *(const uint4*)&sel[(size_t)((b << 11) | i) * 4];
        if ((int)(s.x >> 3) == node) {
            int p = atomicAdd(&scnt, 1);
            if (p < CAP) { se[p] = (i << 3) | (s.x & 7); sv[p] = __uint_as_float(s.z); }
        }
        if ((int)(s.y >> 3) == node) {
            int p = atomicAdd(&scnt, 1);
            if (p < CAP) { se[p] = (i << 3) | (s.y & 7); sv[p] = __uint_as_float(s.w); }
        }
    }
    __syncthreads();
    const int raw = scnt;
    const int n   = min(raw, CAP);

    const int d = tid * 4;
    float ax = 0.f, ay = 0.f, az = 0.f, aw = 0.f;
    int i = 0;
    for (; i + 4 <= n; i += 4) {          // 4 gathers in flight per wave
        const int e0 = se[i], e1 = se[i+1], e2 = se[i+2], e3 = se[i+3];
        const float w0 = sv[i], w1 = sv[i+1], w2 = sv[i+2], w3 = sv[i+3];
        float4 x0 = *(const float4*)&x[(size_t)(((b << 11) | (e0 >> 3)) << 10) + d];
        float4 x1 = *(const float4*)&x[(size_t)(((b << 11) | (e1 >> 3)) << 10) + d];
        float4 x2 = *(const float4*)&x[(size_t)(((b << 11) | (e2 >> 3)) << 10) + d];
        float4 x3 = *(const float4*)&x[(size_t)(((b << 11) | (e3 >> 3)) << 10) + d];
        float4 g0 = *(const float4*)&sg[e0 & 7][d];
        float4 g1 = *(const float4*)&sg[e1 & 7][d];
        float4 g2 = *(const float4*)&sg[e2 & 7][d];
        float4 g3 = *(const float4*)&sg[e3 & 7][d];
        ax = fmaf(w0 * x0.x, g0.x, ax); ay = fmaf(w0 * x0.y, g0.y, ay);
        az = fmaf(w0 * x0.z, g0.z, az); aw = fmaf(w0 * x0.w, g0.w, aw);
        ax = fmaf(w1 * x1.x, g1.x, ax); ay = fmaf(w1 * x1.y, g1.y, ay);
        az = fmaf(w1 * x1.z, g1.z, az); aw = fmaf(w1 * x1.w, g1.w, aw);
        ax = fmaf(w2 * x2.x, g2.x, ax); ay = fmaf(w2 * x2.y, g2.y, ay);
        az = fmaf(w2 * x2.z, g2.z, az); aw = fmaf(w2 * x2.w, g2.w, aw);
        ax = fmaf(w3 * x3.x, g3.x, ax); ay = fmaf(w3 * x3.y, g3.y, ay);
        az = fmaf(w3 * x3.z, g3.z, az); aw = fmaf(w3 * x3.w, g3.w, aw);
    }
    for (; i < n; i++) {
        const int e = se[i];
        const float vv = sv[i];
        float4 xvv = *(const float4*)&x[(size_t)(((b << 11) | (e >> 3)) << 10) + d];
        float4 gh = *(const float4*)&sg[e & 7][d];
        ax = fmaf(vv * xvv.x, gh.x, ax); ay = fmaf(vv * xvv.y, gh.y, ay);
        az = fmaf(vv * xvv.z, gh.z, az); aw = fmaf(vv * xvv.w, gh.w, aw);
    }
    float4 o = {ax, ay, az, aw};
    *(float4*)&out[((size_t)bn << 10) + d] = o;
    if (tid == 0) out[(size_t)B_ * NN * D_ + bn] = (float)raw;   // uncapped count
}

extern "C" void kernel_launch(void* const* d_in, const int* in_sizes, int n_in,
                              void* d_out, int out_size, void* d_ws, size_t ws_size,
                              hipStream_t stream) {
    (void)in_sizes; (void)n_in; (void)out_size; (void)ws_size;
    const float* x    = (const float*)d_in[0];
    const float* W    = (const float*)d_in[1];
    const float* bias = (const float*)d_in[2];
    const float* gv   = (const float*)d_in[3];
    float* out = (float*)d_out;

    // workspace layout (~16.3 MiB)
    ushort* vb = (ushort*)d_ws;                        // 16384*512 bf16 = 16 MiB
    uint*   sel = (uint*)(vb + (size_t)NTOK * NSLOT);  // 16384*4 u32 = 256 KiB

    dim3 g1(NSLOT / BN, NTOK / BM);                    // (4, 128)
    k_gemm<<<g1, 256, 0, stream>>>(x, W, bias, vb);
    k_sel<<<NTOK / 8, 256, 0, stream>>>(vb, x, W, bias, sel);
    k_scatter<<<B_ * NN, 256, 0, stream>>>(x, gv, sel, out);
}

// Round 10
// 180.105 us; speedup vs baseline: 1.5158x; 1.0810x over previous
//
#include <hip/hip_runtime.h>
#include <math.h>

// Problem constants (match reference)
#define B_    8
#define L_    2048
#define D_    1024
#define NN    64        // NUM_NODES
#define NH    8         // NUM_HEADS
#define NSLOT 512       // NN*NH
#define NTOK  (B_*L_)   // 16384
#define CAP   1024      // per-(b,node) match capacity (mean 64, binom std ~8)
#define MAXC  8         // max rescore candidates (margin window holds 2-4 typ.)

typedef __attribute__((ext_vector_type(8))) short short8v;  // 8 bf16 (4 VGPRs)
typedef __attribute__((ext_vector_type(4))) float f32x4;    // MFMA accum

__device__ __forceinline__ uint umaxu(uint a, uint b) { return a > b ? a : b; }
__device__ __forceinline__ uint uminu(uint a, uint b) { return a < b ? a : b; }

__device__ __forceinline__ uint pkbf(float a, float b) {
    return (__float_as_uint(a) >> 16) | (__float_as_uint(b) & 0xFFFF0000u);
}

// async global->LDS, 16B per lane; dest = wave-uniform base + lane*16
__device__ __forceinline__ void gload16(const void* g, void* l) {
    __builtin_amdgcn_global_load_lds(
        (const __attribute__((address_space(1))) void*)g,
        (__attribute__((address_space(3))) void*)l, 16, 0, 0);
}

// ---------------- Kernel 0: fp32 -> bf16 convert (x and W), truncation
// (bit-identical to the r3-r6 in-gemm pk -> vb unchanged -> margin proof holds)
#define NX8 ((size_t)NTOK * D_ / 8)    // 2,097,152 octets
#define NW8 ((size_t)NSLOT * D_ / 8)   // 65,536 octets

__global__ __launch_bounds__(256) void k_cvt(const float* __restrict__ x,
                                             const float* __restrict__ W,
                                             ushort* __restrict__ xb,
                                             ushort* __restrict__ wb) {
    const size_t gid = (size_t)blockIdx.x * 256 + threadIdx.x;
    const float* src;
    ushort* dst;
    size_t e8;
    if (gid < NX8)            { src = x; dst = xb; e8 = gid; }
    else if (gid < NX8 + NW8) { src = W; dst = wb; e8 = gid - NX8; }
    else return;
    const float4 a = *(const float4*)&src[e8 * 8];
    const float4 b = *(const float4*)&src[e8 * 8 + 4];
    uint4 o;
    o.x = pkbf(a.x, a.y); o.y = pkbf(a.z, a.w);
    o.z = pkbf(b.x, b.y); o.w = pkbf(b.z, b.w);
    *(uint4*)&dst[e8 * 8] = o;
}

// ---------------- Kernel 1 (v2): pure-bf16 MFMA GEMM, global_load_lds staging
// vb[m][n] = bf16(sum_k xb[m][k]*wb[n][k] + bias[n]).
// 128x128 tile, BK=64, 4 waves (2x2 of 64x64). LDS [row][8 slots of 8 bf16],
// physical slot = col8 ^ (row&7): linear dest for global_load_lds, inverse
// swizzle applied to the per-lane GLOBAL source, same XOR on ds_read (rule #21).
#define BM 128
#define BN 128
#define BK2 64
#define KT2 (D_ / BK2)   // 16

__global__ __launch_bounds__(256) void k_gemm(const ushort* __restrict__ xb,
                                              const ushort* __restrict__ wb,
                                              const float* __restrict__ bias,
                                              ushort* __restrict__ vb) {
    __shared__ ushort As[2][BM * BK2];   // 16 KiB each buffer
    __shared__ ushort Bs[2][BN * BK2];

    const int tid  = threadIdx.x;
    const int lane = tid & 63;
    const int w    = tid >> 6;          // wave 0..3
    const int wr   = w >> 1, wc = w & 1;

    // XCD-bijective decode (512 = 8 xcd * 4 n * 16 p-groups): the 4 n-blocks of
    // one m-panel get consecutive same-(s&7) ids -> same XCD L2 -> x fetched once
    const int s   = blockIdx.x;
    const int xcd = s & 7;
    const int j   = s >> 3;
    const int m0  = ((((j >> 2) << 3) | xcd)) * BM;   // panel p = (j>>2)*8 + xcd
    const int n0  = (j & 3) * BN;

    const int srow  = lane >> 3;   // 0..7 row within 8-row segment
    const int sslot = lane & 7;    // 16B slot within row

    f32x4 acc[4][4];
#pragma unroll
    for (int i = 0; i < 4; i++)
#pragma unroll
        for (int q = 0; q < 4; q++) acc[i][q] = (f32x4)(0.f);

    auto STAGE = [&](int bufi, int t) {
        const int k0 = t * BK2;
#pragma unroll
        for (int i = 0; i < 4; i++) {
            const int r  = i * 32 + w * 8 + srow;        // tile row 0..127
            const int c8 = sslot ^ (r & 7);              // inverse-swizzled col8
            ushort* dA = &As[bufi][(i * 32 + w * 8) * 64];   // wave-uniform base
            ushort* dB = &Bs[bufi][(i * 32 + w * 8) * 64];
            gload16(&xb[(size_t)(m0 + r) * D_ + k0 + c8 * 8], dA);
            gload16(&wb[(size_t)(n0 + r) * D_ + k0 + c8 * 8], dB);
        }
    };

    auto COMPUTE = [&](int bufi) {
        const ushort* A0 = As[bufi];
        const ushort* B0 = Bs[bufi];
#pragma unroll
        for (int kk = 0; kk < 2; kk++) {
            short8v af[4], bf[4];
#pragma unroll
            for (int mi = 0; mi < 4; mi++) {
                const int row = wr * 64 + mi * 16 + (lane & 15);
                const int c8  = kk * 4 + (lane >> 4);
                af[mi] = *(const short8v*)&A0[row * 64 + ((c8 ^ (row & 7)) << 3)];
            }
#pragma unroll
            for (int ni = 0; ni < 4; ni++) {
                const int row = wc * 64 + ni * 16 + (lane & 15);
                const int c8  = kk * 4 + (lane >> 4);
                bf[ni] = *(const short8v*)&B0[row * 64 + ((c8 ^ (row & 7)) << 3)];
            }
#pragma unroll
            for (int mi = 0; mi < 4; mi++)
#pragma unroll
                for (int ni = 0; ni < 4; ni++)
                    acc[mi][ni] = __builtin_amdgcn_mfma_f32_16x16x32_bf16(af[mi], bf[ni], acc[mi][ni], 0, 0, 0);
        }
    };

    STAGE(0, 0);
    __syncthreads();                 // barrier drains vmcnt -> buf0 ready
    int buf = 0;
    for (int t = 0; t < KT2; t++) {
        if (t + 1 < KT2) STAGE(buf ^ 1, t + 1);   // loads in flight across compute
        COMPUTE(buf);
        __syncthreads();             // one barrier+drain per K-step (T3 minimum)
        buf ^= 1;
    }

    // epilogue (validated r3): C/D layout col = lane&15, row = (lane>>4)*4 + reg
#pragma unroll
    for (int ni = 0; ni < 4; ni++) {
        const int col = n0 + wc * 64 + ni * 16 + (lane & 15);
        const float bv = bias[col];
#pragma unroll
        for (int mi = 0; mi < 4; mi++) {
#pragma unroll
            for (int r = 0; r < 4; r++) {
                const int row = m0 + wr * 64 + mi * 16 + (lane >> 4) * 4 + r;
                vb[(size_t)row * NSLOT + col] = (ushort)(__float_as_uint(acc[mi][ni][r] + bv) >> 16);
            }
        }
    }
}

// ---------------- Kernel 2: 2 tokens/wave, packed-key scan, ballot compaction
// (validated r6; unchanged)
__global__ __launch_bounds__(256) void k_sel(const ushort* __restrict__ vb,
                                             const float* __restrict__ x,
                                             const float* __restrict__ W,
                                             const float* __restrict__ bias,
                                             uint* __restrict__ sel) {
    __shared__ int scand[8][MAXC];

    const int tid   = threadIdx.x;
    const int lane  = tid & 31;
    const int grp   = tid >> 5;
    const int shift = (grp & 1) * 32;
    const int t     = blockIdx.x * 8 + grp;

    const uint4 c0 = *(const uint4*)(vb + (size_t)t * NSLOT + lane * 16);
    const uint4 c1 = *(const uint4*)(vb + (size_t)t * NSLOT + lane * 16 + 8);
    float4 xv[8];
#pragma unroll
    for (int j = 0; j < 8; j++)
        xv[j] = *(const float4*)&x[(size_t)t * D_ + j * 128 + lane * 4];

    const uint u[8] = {c0.x, c0.y, c0.z, c0.w, c1.x, c1.y, c1.z, c1.w};
    float lv[16];
    uint  key[16];
#pragma unroll
    for (int h = 0; h < 8; h++) {
        const uint rl = u[h] & 0xFFFFu, rh = u[h] >> 16;
        lv[2*h]   = __uint_as_float(u[h] << 16);
        lv[2*h+1] = __uint_as_float(u[h] & 0xFFFF0000u);
        const uint ml = rl ^ ((rl & 0x8000u) ? 0xFFFFu : 0x8000u);
        const uint mh = rh ^ ((rh & 0x8000u) ? 0xFFFFu : 0x8000u);
        key[2*h]   = (ml << 9) | (511u - (uint)(lane * 16 + 2*h));
        key[2*h+1] = (mh << 9) | (511u - (uint)(lane * 16 + 2*h + 1));
    }

    auto mrg = [](uint& a1, uint& a2, uint b1, uint b2) {
        const uint m1 = umaxu(a1, b1);
        const uint m2 = (a1 > b1) ? umaxu(a2, b1) : umaxu(b2, a1);
        a1 = m1; a2 = m2;
    };
    uint h1[8], l1[8];
#pragma unroll
    for (int i = 0; i < 8; i++) {
        h1[i] = umaxu(key[2*i], key[2*i+1]);
        l1[i] = uminu(key[2*i], key[2*i+1]);
    }
#pragma unroll
    for (int i = 0; i < 4; i++) mrg(h1[i], l1[i], h1[i+4], l1[i+4]);
#pragma unroll
    for (int i = 0; i < 2; i++) mrg(h1[i], l1[i], h1[i+2], l1[i+2]);
    mrg(h1[0], l1[0], h1[1], l1[1]);
    uint k1 = h1[0], k2 = l1[0];

#pragma unroll
    for (int m = 1; m < 32; m <<= 1) {
        const uint o1 = (uint)__shfl_xor((int)k1, m, 64);
        const uint o2 = (uint)__shfl_xor((int)k2, m, 64);
        mrg(k1, k2, o1, o2);
    }

    const uint m2b = k2 >> 9;
    const uint r2  = (m2b >= 0x8000u) ? (m2b ^ 0x8000u) : (m2b ^ 0xFFFFu);
    const float v2f = __uint_as_float(r2 << 16);
    const float tau = v2f - fmaxf(0.04f, 0.016f * fabsf(v2f));

    uint off = 0;
#pragma unroll
    for (int j = 0; j < 16; j++) {
        const bool p = lv[j] > tau;
        const unsigned long long bal = __ballot(p);
        const uint gm = (uint)(bal >> shift);
        if (p) {
            const uint pos = off + (uint)__popc(gm & ((1u << lane) - 1u));
            if (pos < MAXC) scand[grp][pos] = lane * 16 + j;
        }
        off += (uint)__popc(gm);
    }
    const int nC = min((int)off, MAXC);

    float fv1 = -INFINITY, fv2 = -INFINITY;
    int   fi1 = 1 << 30,   fi2 = 1 << 30;
    auto ins2 = [&](float nv, int ni) {
        if (nv > fv1 || (nv == fv1 && ni < fi1)) { fv2 = fv1; fi2 = fi1; fv1 = nv; fi1 = ni; }
        else if (nv > fv2 || (nv == fv2 && ni < fi2)) { fv2 = nv; fi2 = ni; }
    };
    for (int p0 = 0; p0 < nC; p0 += 2) {
        const bool two = (p0 + 1 < nC);
        const int ia = scand[grp][p0];
        const int ib = two ? scand[grp][p0 + 1] : ia;
        const float* wa = &W[(size_t)ia * D_];
        const float* wb2 = &W[(size_t)ib * D_];
        float da0 = 0.f, da1 = 0.f, db0 = 0.f, db1 = 0.f;
#pragma unroll
        for (int j = 0; j < 8; j++) {
            const float4 av = *(const float4*)&wa[j * 128 + lane * 4];
            const float4 bv = *(const float4*)&wb2[j * 128 + lane * 4];
            const float4 xj = xv[j];
            if (j & 1) {
                da1 = fmaf(xj.x, av.x, da1); da1 = fmaf(xj.y, av.y, da1);
                da1 = fmaf(xj.z, av.z, da1); da1 = fmaf(xj.w, av.w, da1);
                db1 = fmaf(xj.x, bv.x, db1); db1 = fmaf(xj.y, bv.y, db1);
                db1 = fmaf(xj.z, bv.z, db1); db1 = fmaf(xj.w, bv.w, db1);
            } else {
                da0 = fmaf(xj.x, av.x, da0); da0 = fmaf(xj.y, av.y, da0);
                da0 = fmaf(xj.z, av.z, da0); da0 = fmaf(xj.w, av.w, da0);
                db0 = fmaf(xj.x, bv.x, db0); db0 = fmaf(xj.y, bv.y, db0);
                db0 = fmaf(xj.z, bv.z, db0); db0 = fmaf(xj.w, bv.w, db0);
            }
        }
        float da = da0 + da1, db = db0 + db1;
#pragma unroll
        for (int m = 1; m < 32; m <<= 1) {
            da += __shfl_xor(da, m, 64);
            db += __shfl_xor(db, m, 64);
        }
        ins2(da + bias[ia], ia);
        if (two) ins2(db + bias[ib], ib);
    }

    if (lane == 0) {
        uint4 sv;
        sv.x = (uint)fi1;
        sv.y = (uint)fi2;
        sv.z = __float_as_uint(fv1);
        sv.w = __float_as_uint(fv2);
        *(uint4*)&sel[(size_t)t * 4] = sv;
    }
}

// ---------------- Kernel 3: per-(b,node) scan + compact + gather-reduce (r5/r6; unchanged)
__global__ __launch_bounds__(256) void k_scatter(const float* __restrict__ x,
                                                 const float* __restrict__ gv,
                                                 const uint* __restrict__ sel,
                                                 float* __restrict__ out) {
    const int bn   = blockIdx.x;          // b*64 + node
    const int b    = bn >> 6;
    const int node = bn & 63;
    const int tid  = threadIdx.x;

    __shared__ int   se[CAP];             // (l<<3)|head
    __shared__ float sv[CAP];
    __shared__ float sg[NH][D_];          // 32 KiB
    __shared__ int   scnt;

    if (tid == 0) scnt = 0;
    for (int i = tid; i < NH * D_; i += 256)
        sg[i >> 10][i & (D_ - 1)] = gv[((size_t)node << 13) + i];
    __syncthreads();

    for (int i = tid; i < L_; i += 256) {
        uint4 s = *(const uint4*)&sel[(size_t)((b << 11) | i) * 4];
        if ((int)(s.x >> 3) == node) {
            int p = atomicAdd(&scnt, 1);
            if (p < CAP) { se[p] = (i << 3) | (s.x & 7); sv[p] = __uint_as_float(s.z); }
        }
        if ((int)(s.y >> 3) == node) {
            int p = atomicAdd(&scnt, 1);
            if (p < CAP) { se[p] = (i << 3) | (s.y & 7); sv[p] = __uint_as_float(s.w); }
        }
    }
    __syncthreads();
    const int raw = scnt;
    const int n   = min(raw, CAP);

    const int d = tid * 4;
    float ax = 0.f, ay = 0.f, az = 0.f, aw = 0.f;
    int i = 0;
    for (; i + 4 <= n; i += 4) {
        const int e0 = se[i], e1 = se[i+1], e2 = se[i+2], e3 = se[i+3];
        const float w0 = sv[i], w1 = sv[i+1], w2 = sv[i+2], w3 = sv[i+3];
        float4 x0 = *(const float4*)&x[(size_t)(((b << 11) | (e0 >> 3)) << 10) + d];
        float4 x1 = *(const float4*)&x[(size_t)(((b << 11) | (e1 >> 3)) << 10) + d];
        float4 x2 = *(const float4*)&x[(size_t)(((b << 11) | (e2 >> 3)) << 10) + d];
        float4 x3 = *(const float4*)&x[(size_t)(((b << 11) | (e3 >> 3)) << 10) + d];
        float4 g0 = *(const float4*)&sg[e0 & 7][d];
        float4 g1 = *(const float4*)&sg[e1 & 7][d];
        float4 g2 = *(const float4*)&sg[e2 & 7][d];
        float4 g3 = *(const float4*)&sg[e3 & 7][d];
        ax = fmaf(w0 * x0.x, g0.x, ax); ay = fmaf(w0 * x0.y, g0.y, ay);
        az = fmaf(w0 * x0.z, g0.z, az); aw = fmaf(w0 * x0.w, g0.w, aw);
        ax = fmaf(w1 * x1.x, g1.x, ax); ay = fmaf(w1 * x1.y, g1.y, ay);
        az = fmaf(w1 * x1.z, g1.z, az); aw = fmaf(w1 * x1.w, g1.w, aw);
        ax = fmaf(w2 * x2.x, g2.x, ax); ay = fmaf(w2 * x2.y, g2.y, ay);
        az = fmaf(w2 * x2.z, g2.z, az); aw = fmaf(w2 * x2.w, g2.w, aw);
        ax = fmaf(w3 * x3.x, g3.x, ax); ay = fmaf(w3 * x3.y, g3.y, ay);
        az = fmaf(w3 * x3.z, g3.z, az); aw = fmaf(w3 * x3.w, g3.w, aw);
    }
    for (; i < n; i++) {
        const int e = se[i];
        const float vv = sv[i];
        float4 xvv = *(const float4*)&x[(size_t)(((b << 11) | (e >> 3)) << 10) + d];
        float4 gh = *(const float4*)&sg[e & 7][d];
        ax = fmaf(vv * xvv.x, gh.x, ax); ay = fmaf(vv * xvv.y, gh.y, ay);
        az = fmaf(vv * xvv.z, gh.z, az); aw = fmaf(vv * xvv.w, gh.w, aw);
    }
    float4 o = {ax, ay, az, aw};
    *(float4*)&out[((size_t)bn << 10) + d] = o;
    if (tid == 0) out[(size_t)B_ * NN * D_ + bn] = (float)raw;   // uncapped count
}

extern "C" void kernel_launch(void* const* d_in, const int* in_sizes, int n_in,
                              void* d_out, int out_size, void* d_ws, size_t ws_size,
                              hipStream_t stream) {
    (void)in_sizes; (void)n_in; (void)out_size; (void)ws_size;
    const float* x    = (const float*)d_in[0];
    const float* W    = (const float*)d_in[1];
    const float* bias = (const float*)d_in[2];
    const float* gv   = (const float*)d_in[3];
    float* out = (float*)d_out;

    // workspace layout (~49.3 MiB)
    ushort* vb  = (ushort*)d_ws;                        // 16 MiB bf16 logits
    uint*   sel = (uint*)(vb + (size_t)NTOK * NSLOT);   // 256 KiB
    ushort* xb  = (ushort*)(sel + (size_t)NTOK * 4);    // 32 MiB bf16 x
    ushort* wb  = xb + (size_t)NTOK * D_;               // 1 MiB bf16 W

    const int cvtBlocks = (int)((NX8 + NW8) / 256);     // 8448
    k_cvt<<<cvtBlocks, 256, 0, stream>>>(x, W, xb, wb);
    k_gemm<<<512, 256, 0, stream>>>(xb, wb, bias, vb);
    k_sel<<<NTOK / 8, 256, 0, stream>>>(vb, x, W, bias, sel);
    k_scatter<<<B_ * NN, 256, 0, stream>>>(x, gv, sel, out);
}